// Round 12
// baseline (2589.644 us; speedup 1.0000x reference)
//
#include <hip/hip_runtime.h>

// ---------------- problem constants ----------------
#define NN    10000          // nodes
#define FIN   2000           // input features
#define NH    10             // heads
#define C1    128            // layer-1 out channels per head
#define C2    64             // layer-2 out channels per head
#define HC1   1280           // NH*C1
#define HC2   640            // NH*C2
#define MP    10240          // nodes padded to 256*40
#define K1P   2016           // FIN padded to 32 multiple (63*32)

typedef _Float16 f16x8 __attribute__((ext_vector_type(8)));
typedef _Float16 f16x4 __attribute__((ext_vector_type(4)));
typedef _Float16 f16x2 __attribute__((ext_vector_type(2)));
typedef float    f32x4 __attribute__((ext_vector_type(4)));

__device__ __forceinline__ float leaky(float x) { return x > 0.f ? x : 0.2f * x; }

// ---------------- fused prep: cast x->fp16, transpose W1/W2, edge count, LAST-BLOCK CSR scan ----------------
// counts+dcnt zeroed by prior memset. 1-D grid partitioned by role. The last
// block to finish (device-scope done-counter) performs the exclusive scan of
// (counts[i]+1) into rowptr/cursor — removes the separate k_scan dispatch.
#define NCAST (2 * MP)        // 2 blocks per row (Cp4=504)
#define NW1   (63 * 40)
#define NW2   (40 * 20)
__global__ void k_prep(const float* __restrict__ x, _Float16* __restrict__ A1,
                       const float* __restrict__ W1, _Float16* __restrict__ W1t,
                       const float* __restrict__ W2, _Float16* __restrict__ W2t,
                       const int* __restrict__ ei, int* __restrict__ counts, int E,
                       int* __restrict__ dcnt, int* __restrict__ rowptr,
                       int* __restrict__ cursor) {
    __shared__ float tile[32][33];
    __shared__ int ps[256];
    __shared__ int lastFlag;
    int bid = blockIdx.x, t = threadIdx.x;

    if (bid < NCAST) {
        int r = bid >> 1;
        int c = (bid & 1) * 256 + t;
        if (c < K1P / 4) {
            float4 v = make_float4(0.f, 0.f, 0.f, 0.f);
            if (r < NN && c < FIN / 4) v = *(const float4*)(x + (long)r * FIN + 4 * c);
            f16x4 o = {(_Float16)v.x, (_Float16)v.y, (_Float16)v.z, (_Float16)v.w};
            *(f16x4*)(A1 + (long)r * K1P + 4 * c) = o;
        }
    } else if (bid < NCAST + NW1 + NW2) {
        const float* W; _Float16* Wt; int K, N, Kpad, kbase, nbase;
        if (bid < NCAST + NW1) {
            int i = bid - NCAST;
            W = W1; Wt = W1t; K = FIN; N = HC1; Kpad = K1P;
            kbase = (i % 63) * 32; nbase = (i / 63) * 32;
        } else {
            int i = bid - NCAST - NW1;
            W = W2; Wt = W2t; K = HC1; N = HC2; Kpad = HC1;
            kbase = (i % 40) * 32; nbase = (i / 40) * 32;
        }
        int tx = t & 31, ty = t >> 5;
#pragma unroll
        for (int i = 0; i < 4; i++) {
            int k = kbase + ty + i * 8;
            float v = (k < K) ? W[(long)k * N + nbase + tx] : 0.0f;
            tile[ty + i * 8][tx] = v;
        }
        __syncthreads();
#pragma unroll
        for (int i = 0; i < 4; i++) {
            int n = nbase + ty + i * 8;
            Wt[(long)n * Kpad + kbase + tx] = (_Float16)tile[tx][ty + i * 8];
        }
    } else {
        int e = (bid - NCAST - NW1 - NW2) * 256 + t;
        if (e < E) atomicAdd(&counts[ei[E + e]], 1);
    }

    // ---- last-block CSR scan ----
    __threadfence();
    if (t == 0) lastFlag = (atomicAdd(dcnt, 1) == (int)gridDim.x - 1);
    __syncthreads();
    if (!lastFlag) return;
    const int CH = 40;                     // 256*40 = 10240 >= NN+1
    int base = t * CH;
    int loc[CH];
    int sum = 0;
#pragma unroll
    for (int i = 0; i < CH; i++) {
        int idx = base + i;
        int v = (idx < NN) ? (counts[idx] + 1) : 0;
        loc[i] = sum;
        sum += v;
    }
    ps[t] = sum;
    __syncthreads();
    for (int off = 1; off < 256; off <<= 1) {
        int add = (t >= off) ? ps[t - off] : 0;
        __syncthreads();
        ps[t] += add;
        __syncthreads();
    }
    int pre = (t > 0) ? ps[t - 1] : 0;
#pragma unroll
    for (int i = 0; i < CH; i++) {
        int idx = base + i;
        if (idx < NN) { int ex = pre + loc[i]; rowptr[idx] = ex; cursor[idx] = ex; }
    }
    if (t == 255) rowptr[NN] = ps[255];
}

// ---------------- async global->LDS helper ----------------
__device__ __forceinline__ void gl2lds16(const void* g, void* l) {
    __builtin_amdgcn_global_load_lds((const __attribute__((address_space(1))) void*)g,
                                     (__attribute__((address_space(3))) void*)l, 16, 0, 0);
}

// ---------------- fp16 MFMA GEMM + fused attention logits + optional CSR-fill side-job ----------------
template<int MFRAG>
__global__ __launch_bounds__(256, 2) void k_gemm(const _Float16* __restrict__ A,
                                                 const _Float16* __restrict__ Bt,
                                                 _Float16* __restrict__ C, int K, int N,
                                                 int NTN,
                                                 const float* __restrict__ asf,
                                                 const float* __restrict__ adf,
                                                 float* __restrict__ as,
                                                 float* __restrict__ ad,
                                                 int headw, int nblk,
                                                 const int* __restrict__ ei,
                                                 int* __restrict__ cursor,
                                                 int* __restrict__ colidx, int E) {
    constexpr int BM   = MFRAG * 32;
    constexpr int ABUF = BM * 32;               // fp16 elems per A buffer
    constexpr int ASL  = BM / 64;               // A staging slots per thread
    constexpr int WVM  = 0x0F70 | (ASL + 2);    // vmcnt <= loads-per-stage
    __shared__ char smem[3 * ABUF * 2 + 3 * 8192] __attribute__((aligned(16)));
    _Float16* As = (_Float16*)smem;
    _Float16* Bs = (_Float16*)(smem + 3 * ABUF * 2);

    int bid = blockIdx.x;
    if (bid >= nblk) {                          // CSR fill side-job
        int i = (bid - nblk) * 256 + threadIdx.x;
        if (i < E + NN) {
            int s, d;
            if (i < E) { s = ei[i]; d = ei[E + i]; }
            else       { s = i - E; d = i - E; }
            int pos = atomicAdd(&cursor[d], 1);
            colidx[pos] = s;
        }
        return;
    }
    int r = bid & 7, qb = bid >> 3;
    int n_t = qb % NTN;
    int m_t = r + 8 * (qb / NTN);
    int m0 = m_t * BM;
    int n0 = n_t * 128;
    int t = threadIdx.x;
    int lane = t & 63, wave = t >> 6;
    int wr = wave >> 1, wc = wave & 1;
    int lrow = lane & 15, q = lane >> 4;

    f32x4 acc[MFRAG][4] = {};

    int sA[ASL], sB[2];
#pragma unroll
    for (int i = 0; i < ASL; i++) sA[i] = t + 256 * i;
#pragma unroll
    for (int i = 0; i < 2; i++) sB[i] = t + 256 * i;
    const _Float16* Ar[ASL];
    const _Float16* Br[2];
#pragma unroll
    for (int i = 0; i < ASL; i++) {
        int row = sA[i] >> 2, gq = (sA[i] & 3) ^ ((sA[i] >> 3) & 3);
        Ar[i] = A + (long)(m0 + row) * K + gq * 8;
    }
#pragma unroll
    for (int i = 0; i < 2; i++) {
        int row = sB[i] >> 2, gq = (sB[i] & 3) ^ ((sB[i] >> 3) & 3);
        Br[i] = Bt + (long)(n0 + row) * K + gq * 8;
    }

    int aoff[MFRAG], boff[4];
#pragma unroll
    for (int i = 0; i < MFRAG; i++) {
        int rowa = wr * (MFRAG * 16) + i * 16 + lrow;
        aoff[i] = rowa * 32 + ((q ^ ((rowa >> 1) & 3)) << 3);
    }
#pragma unroll
    for (int i = 0; i < 4; i++) {
        int rowb = wc * 64 + i * 16 + lrow;
        boff[i] = rowb * 32 + ((q ^ ((rowb >> 1) & 3)) << 3);
    }

    auto stage = [&](int it, int buf) {
        int k0 = it << 5;
#pragma unroll
        for (int i = 0; i < ASL; i++) gl2lds16(Ar[i] + k0, &As[buf * ABUF + sA[i] * 8]);
#pragma unroll
        for (int i = 0; i < 2; i++) gl2lds16(Br[i] + k0, &Bs[buf * 4096 + sB[i] * 8]);
    };

    int nk = K >> 5;
    stage(0, 0);
    stage(1, 1);
    int cur = 0;
    for (int it = 0; it < nk; it++) {
        if (it + 1 < nk) __builtin_amdgcn_s_waitcnt(WVM);
        else             __builtin_amdgcn_s_waitcnt(0x0F70);
        __builtin_amdgcn_s_barrier();
        int nxt = cur + 2; if (nxt >= 3) nxt -= 3;
        if (it + 2 < nk) stage(it + 2, nxt);

        f16x8 af[MFRAG], bf[4];
#pragma unroll
        for (int i = 0; i < MFRAG; i++) af[i] = *(const f16x8*)&As[cur * ABUF + aoff[i]];
#pragma unroll
        for (int i = 0; i < 4; i++) bf[i] = *(const f16x8*)&Bs[cur * 4096 + boff[i]];
#pragma unroll
        for (int mt = 0; mt < MFRAG; mt++)
#pragma unroll
            for (int nt = 0; nt < 4; nt++)
                acc[mt][nt] = __builtin_amdgcn_mfma_f32_16x16x32_f16(bf[nt], af[mt], acc[mt][nt], 0, 0, 0);
        cur = (cur + 1 == 3) ? 0 : cur + 1;
    }

#pragma unroll
    for (int mt = 0; mt < MFRAG; mt++) {
        int m = m0 + wr * (MFRAG * 16) + mt * 16 + lrow;
#pragma unroll
        for (int nt = 0; nt < 4; nt++) {
            int n = n0 + wc * 64 + nt * 16 + q * 4;
            f16x4 o = {(_Float16)acc[mt][nt][0], (_Float16)acc[mt][nt][1],
                       (_Float16)acc[mt][nt][2], (_Float16)acc[mt][nt][3]};
            *(f16x4*)(C + (long)m * N + n) = o;
        }
    }

    // ---- fused logits: as/ad = h-row . asf/adf per head ----
    float4 av[4], dvv[4];
#pragma unroll
    for (int nt = 0; nt < 4; nt++) {
        av[nt]  = *(const float4*)(asf + n0 + wc * 64 + nt * 16 + q * 4);
        dvv[nt] = *(const float4*)(adf + n0 + wc * 64 + nt * 16 + q * 4);
    }
    __syncthreads();
    float* sAs = (float*)smem;
    float* sAd = (float*)smem + BM * 2;
#pragma unroll
    for (int mt = 0; mt < MFRAG; mt++) {
        float ps = 0.f, pd = 0.f;
#pragma unroll
        for (int nt = 0; nt < 4; nt++) {
            ps += acc[mt][nt][0] * av[nt].x + acc[mt][nt][1] * av[nt].y
                + acc[mt][nt][2] * av[nt].z + acc[mt][nt][3] * av[nt].w;
            pd += acc[mt][nt][0] * dvv[nt].x + acc[mt][nt][1] * dvv[nt].y
                + acc[mt][nt][2] * dvv[nt].z + acc[mt][nt][3] * dvv[nt].w;
        }
        ps += __shfl_xor(ps, 16); ps += __shfl_xor(ps, 32);
        pd += __shfl_xor(pd, 16); pd += __shfl_xor(pd, 32);
        if (q == 0) {
            int rl = wr * (MFRAG * 16) + mt * 16 + lrow;
            sAs[rl * 2 + wc] = ps;
            sAd[rl * 2 + wc] = pd;
        }
    }
    __syncthreads();
    if (t < BM) {
        int m = m0 + t;
        if (m < NN) {
            int hb = n0 / headw;
            if (headw == 128) {
                as[m * NH + hb] = sAs[t * 2] + sAs[t * 2 + 1];
                ad[m * NH + hb] = sAd[t * 2] + sAd[t * 2 + 1];
            } else {
                as[m * NH + hb]     = sAs[t * 2];
                as[m * NH + hb + 1] = sAs[t * 2 + 1];
                ad[m * NH + hb]     = sAd[t * 2];
                ad[m * NH + hb + 1] = sAd[t * 2 + 1];
            }
        }
    }
}

// ---------------- layer-1: 2 nodes/block, fused softmax + f16x8 wide gather -> A2 ----------------
// 320 threads. Softmax stats per wave (heads 2w,2w+1, both nodes). Chunked
// (uniform for any deg): fill alpha chunk -> gather. Gather: threads 0-159 node0,
// 160-319 node1, thread owns 8 channels (f16x8, head = tt>>4). grid = MP/2.
__global__ __launch_bounds__(320) void k_agg1(const int* __restrict__ rowptr,
                                              const int* __restrict__ colidx,
                                              const float* __restrict__ as,
                                              const float* __restrict__ ad,
                                              const _Float16* __restrict__ h,
                                              const float* __restrict__ bias,
                                              _Float16* __restrict__ A2) {
    __shared__ int sidx[2][64];
    __shared__ float sal[2][64 * NH];
    int bid = blockIdx.x, t = threadIdx.x;
    int n0 = 2 * bid;
    int half = t >= 160, tt = t - 160 * half;
    if (n0 >= NN) {                               // pad pair: zeros
        f16x8 z = {(_Float16)0.f, (_Float16)0.f, (_Float16)0.f, (_Float16)0.f,
                   (_Float16)0.f, (_Float16)0.f, (_Float16)0.f, (_Float16)0.f};
        *(f16x8*)(A2 + (long)(n0 + half) * HC1 + 8 * tt) = z;
        return;
    }
    int w = t >> 6, lane = t & 63;
    int k0[2], deg[2];
    k0[0] = rowptr[n0];     deg[0] = rowptr[n0 + 1] - k0[0];
    k0[1] = rowptr[n0 + 1]; deg[1] = rowptr[n0 + 2] - k0[1];

    // softmax stats: wave w, heads 2w/2w+1, nodes 0,1
    float mx[2][2], inv[2][2];
    float2 adv[2];
#pragma unroll
    for (int nd = 0; nd < 2; nd++) {
        adv[nd] = *(const float2*)(ad + (n0 + nd) * NH + 2 * w);
        float e0 = -1e30f, e1 = -1e30f;
        for (int j = lane; j < deg[nd]; j += 64) {
            float2 avv = *(const float2*)(as + (long)colidx[k0[nd] + j] * NH + 2 * w);
            e0 = fmaxf(e0, leaky(avv.x + adv[nd].x));
            e1 = fmaxf(e1, leaky(avv.y + adv[nd].y));
        }
        for (int m = 32; m; m >>= 1) { e0 = fmaxf(e0, __shfl_xor(e0, m)); e1 = fmaxf(e1, __shfl_xor(e1, m)); }
        float s0 = 0.f, s1 = 0.f;
        for (int j = lane; j < deg[nd]; j += 64) {
            float2 avv = *(const float2*)(as + (long)colidx[k0[nd] + j] * NH + 2 * w);
            s0 += __expf(leaky(avv.x + adv[nd].x) - e0);
            s1 += __expf(leaky(avv.y + adv[nd].y) - e1);
        }
        for (int m = 32; m; m >>= 1) { s0 += __shfl_xor(s0, m); s1 += __shfl_xor(s1, m); }
        mx[nd][0] = e0; mx[nd][1] = e1;
        inv[nd][0] = 1.f / (s0 + 1e-16f); inv[nd][1] = 1.f / (s1 + 1e-16f);
    }

    int nd = half;
    int hd = tt >> 4;                    // head for 8-ch ownership (128/8=16 thr/head)
    float acc[8] = {0, 0, 0, 0, 0, 0, 0, 0};
    int cmax = max(deg[0], deg[1]);
    for (int c = 0; c < cmax; c += 64) {
        int cn[2];
        cn[0] = min(64, max(0, deg[0] - c));
        cn[1] = min(64, max(0, deg[1] - c));
        __syncthreads();
        if (w < 2 && lane < cn[w]) sidx[w][lane] = colidx[k0[w] + c + lane];
#pragma unroll
        for (int q2 = 0; q2 < 2; q2++) {
            if (lane < cn[q2]) {
                int src = colidx[k0[q2] + c + lane];
                float2 avv = *(const float2*)(as + (long)src * NH + 2 * w);
                sal[q2][lane * NH + 2 * w]     = __expf(leaky(avv.x + adv[q2].x) - mx[q2][0]) * inv[q2][0];
                sal[q2][lane * NH + 2 * w + 1] = __expf(leaky(avv.y + adv[q2].y) - mx[q2][1]) * inv[q2][1];
            }
        }
        __syncthreads();
        int cnn = cn[nd];
        int j = 0;
        for (; j + 4 <= cnn; j += 4) {            // 4 f16x8 loads in flight
            int s0 = sidx[nd][j], s1b = sidx[nd][j + 1], s2 = sidx[nd][j + 2], s3 = sidx[nd][j + 3];
            float a0 = sal[nd][j * NH + hd], a1 = sal[nd][(j + 1) * NH + hd];
            float a2 = sal[nd][(j + 2) * NH + hd], a3 = sal[nd][(j + 3) * NH + hd];
            f16x8 v0 = *(const f16x8*)(h + (long)s0 * HC1 + 8 * tt);
            f16x8 v1 = *(const f16x8*)(h + (long)s1b * HC1 + 8 * tt);
            f16x8 v2 = *(const f16x8*)(h + (long)s2 * HC1 + 8 * tt);
            f16x8 v3 = *(const f16x8*)(h + (long)s3 * HC1 + 8 * tt);
#pragma unroll
            for (int i = 0; i < 8; i++)
                acc[i] += a0 * (float)v0[i] + a1 * (float)v1[i]
                        + a2 * (float)v2[i] + a3 * (float)v3[i];
        }
        for (; j < cnn; j++) {
            int s0 = sidx[nd][j];
            float a = sal[nd][j * NH + hd];
            f16x8 v = *(const f16x8*)(h + (long)s0 * HC1 + 8 * tt);
#pragma unroll
            for (int i = 0; i < 8; i++) acc[i] += a * (float)v[i];
        }
    }
    f16x8 o;
#pragma unroll
    for (int i = 0; i < 8; i++) {
        float xv = acc[i] + bias[8 * tt + i];
        o[i] = (_Float16)(xv > 0.f ? xv : 0.f);
    }
    *(f16x8*)(A2 + (long)(n0 + nd) * HC1 + 8 * tt) = o;
}

// ---------------- layer-2: 2 nodes/block, fused softmax + f16x4 gather + head mean ----------------
// 320 threads: gather threads 0-159 node0 / 160-319 node1, thread owns 4 channels
// (f16x4, head = tt>>4). grid = NN/2.
__global__ __launch_bounds__(320) void k_agg2(const int* __restrict__ rowptr,
                                              const int* __restrict__ colidx,
                                              const float* __restrict__ as,
                                              const float* __restrict__ ad,
                                              const _Float16* __restrict__ h,
                                              const float* __restrict__ bias,
                                              float* __restrict__ out) {
    __shared__ int sidx[2][64];
    __shared__ float sal[2][64 * NH];
    __shared__ float facc[2][HC2];
    int bid = blockIdx.x, t = threadIdx.x;
    int n0 = 2 * bid;
    int half = t >= 160, tt = t - 160 * half;
    int w = t >> 6, lane = t & 63;
    int k0[2], deg[2];
    k0[0] = rowptr[n0];     deg[0] = rowptr[n0 + 1] - k0[0];
    k0[1] = rowptr[n0 + 1]; deg[1] = rowptr[n0 + 2] - k0[1];

    float mx[2][2], inv[2][2];
    float2 adv[2];
#pragma unroll
    for (int nd2 = 0; nd2 < 2; nd2++) {
        adv[nd2] = *(const float2*)(ad + (n0 + nd2) * NH + 2 * w);
        float e0 = -1e30f, e1 = -1e30f;
        for (int j = lane; j < deg[nd2]; j += 64) {
            float2 avv = *(const float2*)(as + (long)colidx[k0[nd2] + j] * NH + 2 * w);
            e0 = fmaxf(e0, leaky(avv.x + adv[nd2].x));
            e1 = fmaxf(e1, leaky(avv.y + adv[nd2].y));
        }
        for (int m = 32; m; m >>= 1) { e0 = fmaxf(e0, __shfl_xor(e0, m)); e1 = fmaxf(e1, __shfl_xor(e1, m)); }
        float s0 = 0.f, s1 = 0.f;
        for (int j = lane; j < deg[nd2]; j += 64) {
            float2 avv = *(const float2*)(as + (long)colidx[k0[nd2] + j] * NH + 2 * w);
            s0 += __expf(leaky(avv.x + adv[nd2].x) - e0);
            s1 += __expf(leaky(avv.y + adv[nd2].y) - e1);
        }
        for (int m = 32; m; m >>= 1) { s0 += __shfl_xor(s0, m); s1 += __shfl_xor(s1, m); }
        mx[nd2][0] = e0; mx[nd2][1] = e1;
        inv[nd2][0] = 1.f / (s0 + 1e-16f); inv[nd2][1] = 1.f / (s1 + 1e-16f);
    }

    int nd = half;
    int hd = tt >> 4;                    // 64 ch/head / 4 = 16 threads per head
    float a0 = 0.f, a1 = 0.f, a2 = 0.f, a3 = 0.f;
    int cmax = max(deg[0], deg[1]);
    for (int c = 0; c < cmax; c += 64) {
        int cn[2];
        cn[0] = min(64, max(0, deg[0] - c));
        cn[1] = min(64, max(0, deg[1] - c));
        __syncthreads();
        if (w < 2 && lane < cn[w]) sidx[w][lane] = colidx[k0[w] + c + lane];
#pragma unroll
        for (int q2 = 0; q2 < 2; q2++) {
            if (lane < cn[q2]) {
                int src = colidx[k0[q2] + c + lane];
                float2 avv = *(const float2*)(as + (long)src * NH + 2 * w);
                sal[q2][lane * NH + 2 * w]     = __expf(leaky(avv.x + adv[q2].x) - mx[q2][0]) * inv[q2][0];
                sal[q2][lane * NH + 2 * w + 1] = __expf(leaky(avv.y + adv[q2].y) - mx[q2][1]) * inv[q2][1];
            }
        }
        __syncthreads();
        int cnn = cn[nd];
        int j = 0;
        for (; j + 4 <= cnn; j += 4) {
            int s0 = sidx[nd][j], s1b = sidx[nd][j + 1], s2 = sidx[nd][j + 2], s3 = sidx[nd][j + 3];
            float b0 = sal[nd][j * NH + hd], b1 = sal[nd][(j + 1) * NH + hd];
            float b2 = sal[nd][(j + 2) * NH + hd], b3 = sal[nd][(j + 3) * NH + hd];
            f16x4 v0 = *(const f16x4*)(h + (long)s0 * HC2 + 4 * tt);
            f16x4 v1 = *(const f16x4*)(h + (long)s1b * HC2 + 4 * tt);
            f16x4 v2 = *(const f16x4*)(h + (long)s2 * HC2 + 4 * tt);
            f16x4 v3 = *(const f16x4*)(h + (long)s3 * HC2 + 4 * tt);
            a0 += b0 * (float)v0[0] + b1 * (float)v1[0] + b2 * (float)v2[0] + b3 * (float)v3[0];
            a1 += b0 * (float)v0[1] + b1 * (float)v1[1] + b2 * (float)v2[1] + b3 * (float)v3[1];
            a2 += b0 * (float)v0[2] + b1 * (float)v1[2] + b2 * (float)v2[2] + b3 * (float)v3[2];
            a3 += b0 * (float)v0[3] + b1 * (float)v1[3] + b2 * (float)v2[3] + b3 * (float)v3[3];
        }
        for (; j < cnn; j++) {
            int s0 = sidx[nd][j];
            float a = sal[nd][j * NH + hd];
            f16x4 v = *(const f16x4*)(h + (long)s0 * HC2 + 4 * tt);
            a0 += a * (float)v[0]; a1 += a * (float)v[1];
            a2 += a * (float)v[2]; a3 += a * (float)v[3];
        }
    }
    facc[nd][4 * tt]     = a0;
    facc[nd][4 * tt + 1] = a1;
    facc[nd][4 * tt + 2] = a2;
    facc[nd][4 * tt + 3] = a3;
    __syncthreads();
    if (t < 128) {
        int nd2 = t >> 6, cc = t & 63;
        float s = 0.f;
#pragma unroll
        for (int hh = 0; hh < NH; hh++) s += facc[nd2][hh * C2 + cc];
        s = s * 0.1f + bias[cc];
        out[(long)(n0 + nd2) * C2 + cc] = s > 0.f ? s : 0.f;
    }
}

// ---------------- host ----------------
extern "C" void kernel_launch(void* const* d_in, const int* in_sizes, int n_in,
                              void* d_out, int out_size, void* d_ws, size_t ws_size,
                              hipStream_t stream) {
    const float* x      = (const float*)d_in[0];
    const int*   ei     = (const int*)d_in[1];
    const float* W1     = (const float*)d_in[2];
    const float* asrc1  = (const float*)d_in[3];
    const float* adst1  = (const float*)d_in[4];
    const float* b1     = (const float*)d_in[5];
    const float* W2     = (const float*)d_in[6];
    const float* asrc2  = (const float*)d_in[7];
    const float* adst2  = (const float*)d_in[8];
    const float* b2     = (const float*)d_in[9];
    float* out = (float*)d_out;
    const int E  = in_sizes[1] / 2;
    const int EN = E + NN;

    char* base = (char*)d_ws;
    size_t o = 0;
    auto alloc = [&](size_t bytes) { size_t r = o; o += (bytes + 255) & ~(size_t)255; return r; };
    _Float16* A1    = (_Float16*)(base + alloc((size_t)MP * K1P * 2));
    _Float16* W1t   = (_Float16*)(base + alloc((size_t)HC1 * K1P * 2));
    _Float16* A2    = (_Float16*)(base + alloc((size_t)MP * HC1 * 2));
    _Float16* W2t   = (_Float16*)(base + alloc((size_t)HC2 * HC1 * 2));
    _Float16* h1pre = (_Float16*)(base + alloc((size_t)MP * HC1 * 2));
    _Float16* h2pre = (_Float16*)(base + alloc((size_t)MP * HC2 * 2));
    float* as1      = (float*)(base + alloc((size_t)NN * NH * 4));
    float* ad1      = (float*)(base + alloc((size_t)NN * NH * 4));
    float* as2      = (float*)(base + alloc((size_t)NN * NH * 4));
    float* ad2      = (float*)(base + alloc((size_t)NN * NH * 4));
    int* counts     = (int*)(base + alloc((size_t)(NN + 2) * 4));   // counts[NN+1] + dcnt
    int* rowptr     = (int*)(base + alloc((size_t)(NN + 1) * 4));
    int* cursor     = (int*)(base + alloc((size_t)(NN + 1) * 4));
    int* colidx     = (int*)(base + alloc((size_t)EN * 4));
    int* dcnt       = counts + NN + 1;
    (void)ws_size; (void)n_in; (void)out_size;

    const int NCNT = (E + 255) / 256;
    const int FILLB = (EN + 255) / 256;
    const int G1 = 8 * (MP / 256 / 8) * (HC1 / 128);   // 400 gemm1 blocks
    const int G2 = 8 * (MP / 128 / 8) * (HC2 / 128);   // 400 gemm2 blocks (MFRAG=4)

    // ---- zero counts+dcnt, then fused prep (cast + transposes + count + last-block scan) ----
    hipMemsetAsync(counts, 0, (size_t)(NN + 2) * 4, stream);
    k_prep<<<NCAST + NW1 + NW2 + NCNT, 256, 0, stream>>>(x, A1, W1, W1t, W2, W2t, ei, counts, E,
                                                         dcnt, rowptr, cursor);
    // ---- layer 1 GEMM (+ fused logits) with CSR-fill side-job blocks ----
    k_gemm<8><<<G1 + FILLB, 256, 0, stream>>>(A1, W1t, h1pre, K1P, HC1, HC1 / 128,
                                              asrc1, adst1, as1, ad1, C1,
                                              G1, ei, cursor, colidx, E);
    // ---- layer 1: fused softmax/aggregate (2 nodes/block) -> A2 ----
    k_agg1<<<MP / 2, 320, 0, stream>>>(rowptr, colidx, as1, ad1, h1pre, b1, A2);
    // ---- layer 2 GEMM (+ fused logits), BM=128 ----
    k_gemm<4><<<G2, 256, 0, stream>>>(A2, W2t, h2pre, HC1, HC2, HC2 / 128,
                                      asrc2, adst2, as2, ad2, C2,
                                      G2, ei, cursor, colidx, E);
    // ---- layer 2: fused softmax/aggregate + head mean (2 nodes/block) ----
    k_agg2<<<NN / 2, 320, 0, stream>>>(rowptr, colidx, as2, ad2, h2pre, b2, out);
}

// Round 13
// 390.335 us; speedup vs baseline: 6.6344x; 6.6344x over previous
//
#include <hip/hip_runtime.h>

// ---------------- problem constants ----------------
#define NN    10000          // nodes
#define FIN   2000           // input features
#define NH    10             // heads
#define C1    128            // layer-1 out channels per head
#define C2    64             // layer-2 out channels per head
#define HC1   1280           // NH*C1
#define HC2   640            // NH*C2
#define MP    10240          // nodes padded to 256*40
#define K1P   2016           // FIN padded to 32 multiple (63*32)

typedef _Float16 f16x8 __attribute__((ext_vector_type(8)));
typedef _Float16 f16x4 __attribute__((ext_vector_type(4)));
typedef _Float16 f16x2 __attribute__((ext_vector_type(2)));
typedef float    f32x4 __attribute__((ext_vector_type(4)));

__device__ __forceinline__ float leaky(float x) { return x > 0.f ? x : 0.2f * x; }

// ---------------- fused prep: cast x->fp16, transpose W1/W2, edge count ----------------
// counts zeroed by prior memset. 1-D grid partitioned by role.
// NOTE (R12 lesson): NO __threadfence/done-counter here — a device-scope fence
// in every block of a 21k-block grid serialized the whole kernel to 2.3 ms.
#define NCAST (2 * MP)        // 2 blocks per row (Cp4=504)
#define NW1   (63 * 40)
#define NW2   (40 * 20)
__global__ void k_prep(const float* __restrict__ x, _Float16* __restrict__ A1,
                       const float* __restrict__ W1, _Float16* __restrict__ W1t,
                       const float* __restrict__ W2, _Float16* __restrict__ W2t,
                       const int* __restrict__ ei, int* __restrict__ counts, int E) {
    __shared__ float tile[32][33];
    int bid = blockIdx.x, t = threadIdx.x;

    if (bid < NCAST) {
        int r = bid >> 1;
        int c = (bid & 1) * 256 + t;
        if (c < K1P / 4) {
            float4 v = make_float4(0.f, 0.f, 0.f, 0.f);
            if (r < NN && c < FIN / 4) v = *(const float4*)(x + (long)r * FIN + 4 * c);
            f16x4 o = {(_Float16)v.x, (_Float16)v.y, (_Float16)v.z, (_Float16)v.w};
            *(f16x4*)(A1 + (long)r * K1P + 4 * c) = o;
        }
    } else if (bid < NCAST + NW1 + NW2) {
        const float* W; _Float16* Wt; int K, N, Kpad, kbase, nbase;
        if (bid < NCAST + NW1) {
            int i = bid - NCAST;
            W = W1; Wt = W1t; K = FIN; N = HC1; Kpad = K1P;
            kbase = (i % 63) * 32; nbase = (i / 63) * 32;
        } else {
            int i = bid - NCAST - NW1;
            W = W2; Wt = W2t; K = HC1; N = HC2; Kpad = HC1;
            kbase = (i % 40) * 32; nbase = (i / 40) * 32;
        }
        int tx = t & 31, ty = t >> 5;
#pragma unroll
        for (int i = 0; i < 4; i++) {
            int k = kbase + ty + i * 8;
            float v = (k < K) ? W[(long)k * N + nbase + tx] : 0.0f;
            tile[ty + i * 8][tx] = v;
        }
        __syncthreads();
#pragma unroll
        for (int i = 0; i < 4; i++) {
            int n = nbase + ty + i * 8;
            Wt[(long)n * Kpad + kbase + tx] = (_Float16)tile[tx][ty + i * 8];
        }
    } else {
        int e = (bid - NCAST - NW1 - NW2) * 256 + t;
        if (e < E) atomicAdd(&counts[ei[E + e]], 1);
    }
}

// ---------------- CSR scan: single-pass chunked exclusive scan of (counts[i]+1) ----------------
__global__ void k_scan(const int* __restrict__ counts, int* rowptr, int* cursor, int n) {
    __shared__ int s[1024];
    int t = threadIdx.x;
    const int CH = (NN + 1023) / 1024;     // 10
    int base = t * CH;
    int loc[CH];
    int sum = 0;
#pragma unroll
    for (int i = 0; i < CH; i++) {
        int idx = base + i;
        int v = (idx < n) ? (counts[idx] + 1) : 0;
        loc[i] = sum;
        sum += v;
    }
    s[t] = sum;
    __syncthreads();
    for (int off = 1; off < 1024; off <<= 1) {
        int add = (t >= off) ? s[t - off] : 0;
        __syncthreads();
        s[t] += add;
        __syncthreads();
    }
    int pre = (t > 0) ? s[t - 1] : 0;
#pragma unroll
    for (int i = 0; i < CH; i++) {
        int idx = base + i;
        if (idx < n) { int ex = pre + loc[i]; rowptr[idx] = ex; cursor[idx] = ex; }
    }
    if (t == 1023) rowptr[n] = s[1023];
}

// ---------------- async global->LDS helper ----------------
__device__ __forceinline__ void gl2lds16(const void* g, void* l) {
    __builtin_amdgcn_global_load_lds((const __attribute__((address_space(1))) void*)g,
                                     (__attribute__((address_space(3))) void*)l, 16, 0, 0);
}

// ---------------- fp16 MFMA GEMM + fused attention logits + optional CSR-fill side-job ----------------
template<int MFRAG>
__global__ __launch_bounds__(256, 2) void k_gemm(const _Float16* __restrict__ A,
                                                 const _Float16* __restrict__ Bt,
                                                 _Float16* __restrict__ C, int K, int N,
                                                 int NTN,
                                                 const float* __restrict__ asf,
                                                 const float* __restrict__ adf,
                                                 float* __restrict__ as,
                                                 float* __restrict__ ad,
                                                 int headw, int nblk,
                                                 const int* __restrict__ ei,
                                                 int* __restrict__ cursor,
                                                 int* __restrict__ colidx, int E) {
    constexpr int BM   = MFRAG * 32;
    constexpr int ABUF = BM * 32;               // fp16 elems per A buffer
    constexpr int ASL  = BM / 64;               // A staging slots per thread
    constexpr int WVM  = 0x0F70 | (ASL + 2);    // vmcnt <= loads-per-stage
    __shared__ char smem[3 * ABUF * 2 + 3 * 8192] __attribute__((aligned(16)));
    _Float16* As = (_Float16*)smem;
    _Float16* Bs = (_Float16*)(smem + 3 * ABUF * 2);

    int bid = blockIdx.x;
    if (bid >= nblk) {                          // CSR fill side-job
        int i = (bid - nblk) * 256 + threadIdx.x;
        if (i < E + NN) {
            int s, d;
            if (i < E) { s = ei[i]; d = ei[E + i]; }
            else       { s = i - E; d = i - E; }
            int pos = atomicAdd(&cursor[d], 1);
            colidx[pos] = s;
        }
        return;
    }
    int r = bid & 7, qb = bid >> 3;
    int n_t = qb % NTN;
    int m_t = r + 8 * (qb / NTN);
    int m0 = m_t * BM;
    int n0 = n_t * 128;
    int t = threadIdx.x;
    int lane = t & 63, wave = t >> 6;
    int wr = wave >> 1, wc = wave & 1;
    int lrow = lane & 15, q = lane >> 4;

    f32x4 acc[MFRAG][4] = {};

    int sA[ASL], sB[2];
#pragma unroll
    for (int i = 0; i < ASL; i++) sA[i] = t + 256 * i;
#pragma unroll
    for (int i = 0; i < 2; i++) sB[i] = t + 256 * i;
    const _Float16* Ar[ASL];
    const _Float16* Br[2];
#pragma unroll
    for (int i = 0; i < ASL; i++) {
        int row = sA[i] >> 2, gq = (sA[i] & 3) ^ ((sA[i] >> 3) & 3);
        Ar[i] = A + (long)(m0 + row) * K + gq * 8;
    }
#pragma unroll
    for (int i = 0; i < 2; i++) {
        int row = sB[i] >> 2, gq = (sB[i] & 3) ^ ((sB[i] >> 3) & 3);
        Br[i] = Bt + (long)(n0 + row) * K + gq * 8;
    }

    int aoff[MFRAG], boff[4];
#pragma unroll
    for (int i = 0; i < MFRAG; i++) {
        int rowa = wr * (MFRAG * 16) + i * 16 + lrow;
        aoff[i] = rowa * 32 + ((q ^ ((rowa >> 1) & 3)) << 3);
    }
#pragma unroll
    for (int i = 0; i < 4; i++) {
        int rowb = wc * 64 + i * 16 + lrow;
        boff[i] = rowb * 32 + ((q ^ ((rowb >> 1) & 3)) << 3);
    }

    auto stage = [&](int it, int buf) {
        int k0 = it << 5;
#pragma unroll
        for (int i = 0; i < ASL; i++) gl2lds16(Ar[i] + k0, &As[buf * ABUF + sA[i] * 8]);
#pragma unroll
        for (int i = 0; i < 2; i++) gl2lds16(Br[i] + k0, &Bs[buf * 4096 + sB[i] * 8]);
    };

    int nk = K >> 5;
    stage(0, 0);
    stage(1, 1);
    int cur = 0;
    for (int it = 0; it < nk; it++) {
        if (it + 1 < nk) __builtin_amdgcn_s_waitcnt(WVM);
        else             __builtin_amdgcn_s_waitcnt(0x0F70);
        __builtin_amdgcn_s_barrier();
        int nxt = cur + 2; if (nxt >= 3) nxt -= 3;
        if (it + 2 < nk) stage(it + 2, nxt);

        f16x8 af[MFRAG], bf[4];
#pragma unroll
        for (int i = 0; i < MFRAG; i++) af[i] = *(const f16x8*)&As[cur * ABUF + aoff[i]];
#pragma unroll
        for (int i = 0; i < 4; i++) bf[i] = *(const f16x8*)&Bs[cur * 4096 + boff[i]];
#pragma unroll
        for (int mt = 0; mt < MFRAG; mt++)
#pragma unroll
            for (int nt = 0; nt < 4; nt++)
                acc[mt][nt] = __builtin_amdgcn_mfma_f32_16x16x32_f16(bf[nt], af[mt], acc[mt][nt], 0, 0, 0);
        cur = (cur + 1 == 3) ? 0 : cur + 1;
    }

#pragma unroll
    for (int mt = 0; mt < MFRAG; mt++) {
        int m = m0 + wr * (MFRAG * 16) + mt * 16 + lrow;
#pragma unroll
        for (int nt = 0; nt < 4; nt++) {
            int n = n0 + wc * 64 + nt * 16 + q * 4;
            f16x4 o = {(_Float16)acc[mt][nt][0], (_Float16)acc[mt][nt][1],
                       (_Float16)acc[mt][nt][2], (_Float16)acc[mt][nt][3]};
            *(f16x4*)(C + (long)m * N + n) = o;
        }
    }

    // ---- fused logits: as/ad = h-row . asf/adf per head ----
    float4 av[4], dvv[4];
#pragma unroll
    for (int nt = 0; nt < 4; nt++) {
        av[nt]  = *(const float4*)(asf + n0 + wc * 64 + nt * 16 + q * 4);
        dvv[nt] = *(const float4*)(adf + n0 + wc * 64 + nt * 16 + q * 4);
    }
    __syncthreads();
    float* sAs = (float*)smem;
    float* sAd = (float*)smem + BM * 2;
#pragma unroll
    for (int mt = 0; mt < MFRAG; mt++) {
        float ps = 0.f, pd = 0.f;
#pragma unroll
        for (int nt = 0; nt < 4; nt++) {
            ps += acc[mt][nt][0] * av[nt].x + acc[mt][nt][1] * av[nt].y
                + acc[mt][nt][2] * av[nt].z + acc[mt][nt][3] * av[nt].w;
            pd += acc[mt][nt][0] * dvv[nt].x + acc[mt][nt][1] * dvv[nt].y
                + acc[mt][nt][2] * dvv[nt].z + acc[mt][nt][3] * dvv[nt].w;
        }
        ps += __shfl_xor(ps, 16); ps += __shfl_xor(ps, 32);
        pd += __shfl_xor(pd, 16); pd += __shfl_xor(pd, 32);
        if (q == 0) {
            int rl = wr * (MFRAG * 16) + mt * 16 + lrow;
            sAs[rl * 2 + wc] = ps;
            sAd[rl * 2 + wc] = pd;
        }
    }
    __syncthreads();
    if (t < BM) {
        int m = m0 + t;
        if (m < NN) {
            int hb = n0 / headw;
            if (headw == 128) {
                as[m * NH + hb] = sAs[t * 2] + sAs[t * 2 + 1];
                ad[m * NH + hb] = sAd[t * 2] + sAd[t * 2 + 1];
            } else {
                as[m * NH + hb]     = sAs[t * 2];
                as[m * NH + hb + 1] = sAs[t * 2 + 1];
                ad[m * NH + hb]     = sAd[t * 2];
                ad[m * NH + hb + 1] = sAd[t * 2 + 1];
            }
        }
    }
}

// ---------------- layer-1: 2 nodes/block, fused softmax + f16x8 wide gather -> A2 ----------------
__global__ __launch_bounds__(320) void k_agg1(const int* __restrict__ rowptr,
                                              const int* __restrict__ colidx,
                                              const float* __restrict__ as,
                                              const float* __restrict__ ad,
                                              const _Float16* __restrict__ h,
                                              const float* __restrict__ bias,
                                              _Float16* __restrict__ A2) {
    __shared__ int sidx[2][64];
    __shared__ float sal[2][64 * NH];
    int bid = blockIdx.x, t = threadIdx.x;
    int n0 = 2 * bid;
    int half = t >= 160, tt = t - 160 * half;
    if (n0 >= NN) {                               // pad pair: zeros
        f16x8 z = {(_Float16)0.f, (_Float16)0.f, (_Float16)0.f, (_Float16)0.f,
                   (_Float16)0.f, (_Float16)0.f, (_Float16)0.f, (_Float16)0.f};
        *(f16x8*)(A2 + (long)(n0 + half) * HC1 + 8 * tt) = z;
        return;
    }
    int w = t >> 6, lane = t & 63;
    int k0[2], deg[2];
    k0[0] = rowptr[n0];     deg[0] = rowptr[n0 + 1] - k0[0];
    k0[1] = rowptr[n0 + 1]; deg[1] = rowptr[n0 + 2] - k0[1];

    float mx[2][2], inv[2][2];
    float2 adv[2];
#pragma unroll
    for (int nd = 0; nd < 2; nd++) {
        adv[nd] = *(const float2*)(ad + (n0 + nd) * NH + 2 * w);
        float e0 = -1e30f, e1 = -1e30f;
        for (int j = lane; j < deg[nd]; j += 64) {
            float2 avv = *(const float2*)(as + (long)colidx[k0[nd] + j] * NH + 2 * w);
            e0 = fmaxf(e0, leaky(avv.x + adv[nd].x));
            e1 = fmaxf(e1, leaky(avv.y + adv[nd].y));
        }
        for (int m = 32; m; m >>= 1) { e0 = fmaxf(e0, __shfl_xor(e0, m)); e1 = fmaxf(e1, __shfl_xor(e1, m)); }
        float s0 = 0.f, s1 = 0.f;
        for (int j = lane; j < deg[nd]; j += 64) {
            float2 avv = *(const float2*)(as + (long)colidx[k0[nd] + j] * NH + 2 * w);
            s0 += __expf(leaky(avv.x + adv[nd].x) - e0);
            s1 += __expf(leaky(avv.y + adv[nd].y) - e1);
        }
        for (int m = 32; m; m >>= 1) { s0 += __shfl_xor(s0, m); s1 += __shfl_xor(s1, m); }
        mx[nd][0] = e0; mx[nd][1] = e1;
        inv[nd][0] = 1.f / (s0 + 1e-16f); inv[nd][1] = 1.f / (s1 + 1e-16f);
    }

    int nd = half;
    int hd = tt >> 4;                    // head for 8-ch ownership (128/8=16 thr/head)
    float acc[8] = {0, 0, 0, 0, 0, 0, 0, 0};
    int cmax = max(deg[0], deg[1]);
    for (int c = 0; c < cmax; c += 64) {
        int cn[2];
        cn[0] = min(64, max(0, deg[0] - c));
        cn[1] = min(64, max(0, deg[1] - c));
        __syncthreads();
        if (w < 2 && lane < cn[w]) sidx[w][lane] = colidx[k0[w] + c + lane];
#pragma unroll
        for (int q2 = 0; q2 < 2; q2++) {
            if (lane < cn[q2]) {
                int src = colidx[k0[q2] + c + lane];
                float2 avv = *(const float2*)(as + (long)src * NH + 2 * w);
                sal[q2][lane * NH + 2 * w]     = __expf(leaky(avv.x + adv[q2].x) - mx[q2][0]) * inv[q2][0];
                sal[q2][lane * NH + 2 * w + 1] = __expf(leaky(avv.y + adv[q2].y) - mx[q2][1]) * inv[q2][1];
            }
        }
        __syncthreads();
        int cnn = cn[nd];
        int j = 0;
        for (; j + 4 <= cnn; j += 4) {            // 4 f16x8 loads in flight
            int s0 = sidx[nd][j], s1b = sidx[nd][j + 1], s2 = sidx[nd][j + 2], s3 = sidx[nd][j + 3];
            float a0 = sal[nd][j * NH + hd], a1 = sal[nd][(j + 1) * NH + hd];
            float a2 = sal[nd][(j + 2) * NH + hd], a3 = sal[nd][(j + 3) * NH + hd];
            f16x8 v0 = *(const f16x8*)(h + (long)s0 * HC1 + 8 * tt);
            f16x8 v1 = *(const f16x8*)(h + (long)s1b * HC1 + 8 * tt);
            f16x8 v2 = *(const f16x8*)(h + (long)s2 * HC1 + 8 * tt);
            f16x8 v3 = *(const f16x8*)(h + (long)s3 * HC1 + 8 * tt);
#pragma unroll
            for (int i = 0; i < 8; i++)
                acc[i] += a0 * (float)v0[i] + a1 * (float)v1[i]
                        + a2 * (float)v2[i] + a3 * (float)v3[i];
        }
        for (; j < cnn; j++) {
            int s0 = sidx[nd][j];
            float a = sal[nd][j * NH + hd];
            f16x8 v = *(const f16x8*)(h + (long)s0 * HC1 + 8 * tt);
#pragma unroll
            for (int i = 0; i < 8; i++) acc[i] += a * (float)v[i];
        }
    }
    f16x8 o;
#pragma unroll
    for (int i = 0; i < 8; i++) {
        float xv = acc[i] + bias[8 * tt + i];
        o[i] = (_Float16)(xv > 0.f ? xv : 0.f);
    }
    *(f16x8*)(A2 + (long)(n0 + nd) * HC1 + 8 * tt) = o;
}

// ---------------- layer-2: 2 nodes/block, fused softmax + f16x4 gather + head mean ----------------
__global__ __launch_bounds__(320) void k_agg2(const int* __restrict__ rowptr,
                                              const int* __restrict__ colidx,
                                              const float* __restrict__ as,
                                              const float* __restrict__ ad,
                                              const _Float16* __restrict__ h,
                                              const float* __restrict__ bias,
                                              float* __restrict__ out) {
    __shared__ int sidx[2][64];
    __shared__ float sal[2][64 * NH];
    __shared__ float facc[2][HC2];
    int bid = blockIdx.x, t = threadIdx.x;
    int n0 = 2 * bid;
    int half = t >= 160, tt = t - 160 * half;
    int w = t >> 6, lane = t & 63;
    int k0[2], deg[2];
    k0[0] = rowptr[n0];     deg[0] = rowptr[n0 + 1] - k0[0];
    k0[1] = rowptr[n0 + 1]; deg[1] = rowptr[n0 + 2] - k0[1];

    float mx[2][2], inv[2][2];
    float2 adv[2];
#pragma unroll
    for (int nd2 = 0; nd2 < 2; nd2++) {
        adv[nd2] = *(const float2*)(ad + (n0 + nd2) * NH + 2 * w);
        float e0 = -1e30f, e1 = -1e30f;
        for (int j = lane; j < deg[nd2]; j += 64) {
            float2 avv = *(const float2*)(as + (long)colidx[k0[nd2] + j] * NH + 2 * w);
            e0 = fmaxf(e0, leaky(avv.x + adv[nd2].x));
            e1 = fmaxf(e1, leaky(avv.y + adv[nd2].y));
        }
        for (int m = 32; m; m >>= 1) { e0 = fmaxf(e0, __shfl_xor(e0, m)); e1 = fmaxf(e1, __shfl_xor(e1, m)); }
        float s0 = 0.f, s1 = 0.f;
        for (int j = lane; j < deg[nd2]; j += 64) {
            float2 avv = *(const float2*)(as + (long)colidx[k0[nd2] + j] * NH + 2 * w);
            s0 += __expf(leaky(avv.x + adv[nd2].x) - e0);
            s1 += __expf(leaky(avv.y + adv[nd2].y) - e1);
        }
        for (int m = 32; m; m >>= 1) { s0 += __shfl_xor(s0, m); s1 += __shfl_xor(s1, m); }
        mx[nd2][0] = e0; mx[nd2][1] = e1;
        inv[nd2][0] = 1.f / (s0 + 1e-16f); inv[nd2][1] = 1.f / (s1 + 1e-16f);
    }

    int nd = half;
    int hd = tt >> 4;                    // 64 ch/head / 4 = 16 threads per head
    float a0 = 0.f, a1 = 0.f, a2 = 0.f, a3 = 0.f;
    int cmax = max(deg[0], deg[1]);
    for (int c = 0; c < cmax; c += 64) {
        int cn[2];
        cn[0] = min(64, max(0, deg[0] - c));
        cn[1] = min(64, max(0, deg[1] - c));
        __syncthreads();
        if (w < 2 && lane < cn[w]) sidx[w][lane] = colidx[k0[w] + c + lane];
#pragma unroll
        for (int q2 = 0; q2 < 2; q2++) {
            if (lane < cn[q2]) {
                int src = colidx[k0[q2] + c + lane];
                float2 avv = *(const float2*)(as + (long)src * NH + 2 * w);
                sal[q2][lane * NH + 2 * w]     = __expf(leaky(avv.x + adv[q2].x) - mx[q2][0]) * inv[q2][0];
                sal[q2][lane * NH + 2 * w + 1] = __expf(leaky(avv.y + adv[q2].y) - mx[q2][1]) * inv[q2][1];
            }
        }
        __syncthreads();
        int cnn = cn[nd];
        int j = 0;
        for (; j + 4 <= cnn; j += 4) {
            int s0 = sidx[nd][j], s1b = sidx[nd][j + 1], s2 = sidx[nd][j + 2], s3 = sidx[nd][j + 3];
            float b0 = sal[nd][j * NH + hd], b1 = sal[nd][(j + 1) * NH + hd];
            float b2 = sal[nd][(j + 2) * NH + hd], b3 = sal[nd][(j + 3) * NH + hd];
            f16x4 v0 = *(const f16x4*)(h + (long)s0 * HC2 + 4 * tt);
            f16x4 v1 = *(const f16x4*)(h + (long)s1b * HC2 + 4 * tt);
            f16x4 v2 = *(const f16x4*)(h + (long)s2 * HC2 + 4 * tt);
            f16x4 v3 = *(const f16x4*)(h + (long)s3 * HC2 + 4 * tt);
            a0 += b0 * (float)v0[0] + b1 * (float)v1[0] + b2 * (float)v2[0] + b3 * (float)v3[0];
            a1 += b0 * (float)v0[1] + b1 * (float)v1[1] + b2 * (float)v2[1] + b3 * (float)v3[1];
            a2 += b0 * (float)v0[2] + b1 * (float)v1[2] + b2 * (float)v2[2] + b3 * (float)v3[2];
            a3 += b0 * (float)v0[3] + b1 * (float)v1[3] + b2 * (float)v2[3] + b3 * (float)v3[3];
        }
        for (; j < cnn; j++) {
            int s0 = sidx[nd][j];
            float a = sal[nd][j * NH + hd];
            f16x4 v = *(const f16x4*)(h + (long)s0 * HC2 + 4 * tt);
            a0 += a * (float)v[0]; a1 += a * (float)v[1];
            a2 += a * (float)v[2]; a3 += a * (float)v[3];
        }
    }
    facc[nd][4 * tt]     = a0;
    facc[nd][4 * tt + 1] = a1;
    facc[nd][4 * tt + 2] = a2;
    facc[nd][4 * tt + 3] = a3;
    __syncthreads();
    if (t < 128) {
        int nd2 = t >> 6, cc = t & 63;
        float s = 0.f;
#pragma unroll
        for (int hh = 0; hh < NH; hh++) s += facc[nd2][hh * C2 + cc];
        s = s * 0.1f + bias[cc];
        out[(long)(n0 + nd2) * C2 + cc] = s > 0.f ? s : 0.f;
    }
}

// ---------------- host ----------------
extern "C" void kernel_launch(void* const* d_in, const int* in_sizes, int n_in,
                              void* d_out, int out_size, void* d_ws, size_t ws_size,
                              hipStream_t stream) {
    const float* x      = (const float*)d_in[0];
    const int*   ei     = (const int*)d_in[1];
    const float* W1     = (const float*)d_in[2];
    const float* asrc1  = (const float*)d_in[3];
    const float* adst1  = (const float*)d_in[4];
    const float* b1     = (const float*)d_in[5];
    const float* W2     = (const float*)d_in[6];
    const float* asrc2  = (const float*)d_in[7];
    const float* adst2  = (const float*)d_in[8];
    const float* b2     = (const float*)d_in[9];
    float* out = (float*)d_out;
    const int E  = in_sizes[1] / 2;
    const int EN = E + NN;

    char* base = (char*)d_ws;
    size_t o = 0;
    auto alloc = [&](size_t bytes) { size_t r = o; o += (bytes + 255) & ~(size_t)255; return r; };
    _Float16* A1    = (_Float16*)(base + alloc((size_t)MP * K1P * 2));
    _Float16* W1t   = (_Float16*)(base + alloc((size_t)HC1 * K1P * 2));
    _Float16* A2    = (_Float16*)(base + alloc((size_t)MP * HC1 * 2));
    _Float16* W2t   = (_Float16*)(base + alloc((size_t)HC2 * HC1 * 2));
    _Float16* h1pre = (_Float16*)(base + alloc((size_t)MP * HC1 * 2));
    _Float16* h2pre = (_Float16*)(base + alloc((size_t)MP * HC2 * 2));
    float* as1      = (float*)(base + alloc((size_t)NN * NH * 4));
    float* ad1      = (float*)(base + alloc((size_t)NN * NH * 4));
    float* as2      = (float*)(base + alloc((size_t)NN * NH * 4));
    float* ad2      = (float*)(base + alloc((size_t)NN * NH * 4));
    int* counts     = (int*)(base + alloc((size_t)(NN + 1) * 4));
    int* rowptr     = (int*)(base + alloc((size_t)(NN + 1) * 4));
    int* cursor     = (int*)(base + alloc((size_t)(NN + 1) * 4));
    int* colidx     = (int*)(base + alloc((size_t)EN * 4));
    (void)ws_size; (void)n_in; (void)out_size;

    const int NCNT = (E + 255) / 256;
    const int FILLB = (EN + 255) / 256;
    const int G1 = 8 * (MP / 256 / 8) * (HC1 / 128);   // 400 gemm1 blocks
    const int G2 = 8 * (MP / 128 / 8) * (HC2 / 128);   // 400 gemm2 blocks (MFRAG=4)

    // ---- zero counts, then fused prep (cast + transposes + edge count) ----
    hipMemsetAsync(counts, 0, (size_t)(NN + 1) * 4, stream);
    k_prep<<<NCAST + NW1 + NW2 + NCNT, 256, 0, stream>>>(x, A1, W1, W1t, W2, W2t, ei, counts, E);
    // ---- CSR scan (rowptr/cursor) ----
    k_scan<<<1, 1024, 0, stream>>>(counts, rowptr, cursor, NN);
    // ---- layer 1 GEMM (+ fused logits) with CSR-fill side-job blocks ----
    k_gemm<8><<<G1 + FILLB, 256, 0, stream>>>(A1, W1t, h1pre, K1P, HC1, HC1 / 128,
                                              asrc1, adst1, as1, ad1, C1,
                                              G1, ei, cursor, colidx, E);
    // ---- layer 1: fused softmax/aggregate (2 nodes/block) -> A2 ----
    k_agg1<<<MP / 2, 320, 0, stream>>>(rowptr, colidx, as1, ad1, h1pre, b1, A2);
    // ---- layer 2 GEMM (+ fused logits), BM=128 ----
    k_gemm<4><<<G2, 256, 0, stream>>>(A2, W2t, h2pre, HC1, HC2, HC2 / 128,
                                      asrc2, adst2, as2, ad2, C2,
                                      G2, ei, cursor, colidx, E);
    // ---- layer 2: fused softmax/aggregate + head mean (2 nodes/block) ----
    k_agg2<<<NN / 2, 320, 0, stream>>>(rowptr, colidx, as2, ad2, h2pre, b2, out);
}

// Round 14
// 366.189 us; speedup vs baseline: 7.0719x; 1.0659x over previous
//
#include <hip/hip_runtime.h>

// ---------------- problem constants ----------------
#define NN    10000          // nodes
#define FIN   2000           // input features
#define NH    10             // heads
#define C1    128            // layer-1 out channels per head
#define C2    64             // layer-2 out channels per head
#define HC1   1280           // NH*C1
#define HC2   640            // NH*C2
#define MP    10240          // nodes padded to 256*40
#define K1P   2016           // FIN padded to 32 multiple (63*32)

typedef _Float16 f16x8 __attribute__((ext_vector_type(8)));
typedef _Float16 f16x4 __attribute__((ext_vector_type(4)));
typedef _Float16 f16x2 __attribute__((ext_vector_type(2)));
typedef float    f32x4 __attribute__((ext_vector_type(4)));

__device__ __forceinline__ float leaky(float x) { return x > 0.f ? x : 0.2f * x; }

// ---------------- fused prep: cast x->fp16, transpose W1/W2, edge count ----------------
// counts zeroed by prior memset. 1-D grid partitioned by role.
// NOTE (R12 lesson): NO __threadfence/done-counter here — a device-scope fence
// in every block of a 21k-block grid serialized the whole kernel to 2.3 ms.
#define NCAST (2 * MP)        // 2 blocks per row (Cp4=504)
#define NW1   (63 * 40)
#define NW2   (40 * 20)
__global__ void k_prep(const float* __restrict__ x, _Float16* __restrict__ A1,
                       const float* __restrict__ W1, _Float16* __restrict__ W1t,
                       const float* __restrict__ W2, _Float16* __restrict__ W2t,
                       const int* __restrict__ ei, int* __restrict__ counts, int E) {
    __shared__ float tile[32][33];
    int bid = blockIdx.x, t = threadIdx.x;

    if (bid < NCAST) {
        int r = bid >> 1;
        int c = (bid & 1) * 256 + t;
        if (c < K1P / 4) {
            float4 v = make_float4(0.f, 0.f, 0.f, 0.f);
            if (r < NN && c < FIN / 4) v = *(const float4*)(x + (long)r * FIN + 4 * c);
            f16x4 o = {(_Float16)v.x, (_Float16)v.y, (_Float16)v.z, (_Float16)v.w};
            *(f16x4*)(A1 + (long)r * K1P + 4 * c) = o;
        }
    } else if (bid < NCAST + NW1 + NW2) {
        const float* W; _Float16* Wt; int K, N, Kpad, kbase, nbase;
        if (bid < NCAST + NW1) {
            int i = bid - NCAST;
            W = W1; Wt = W1t; K = FIN; N = HC1; Kpad = K1P;
            kbase = (i % 63) * 32; nbase = (i / 63) * 32;
        } else {
            int i = bid - NCAST - NW1;
            W = W2; Wt = W2t; K = HC1; N = HC2; Kpad = HC1;
            kbase = (i % 40) * 32; nbase = (i / 40) * 32;
        }
        int tx = t & 31, ty = t >> 5;
#pragma unroll
        for (int i = 0; i < 4; i++) {
            int k = kbase + ty + i * 8;
            float v = (k < K) ? W[(long)k * N + nbase + tx] : 0.0f;
            tile[ty + i * 8][tx] = v;
        }
        __syncthreads();
#pragma unroll
        for (int i = 0; i < 4; i++) {
            int n = nbase + ty + i * 8;
            Wt[(long)n * Kpad + kbase + tx] = (_Float16)tile[tx][ty + i * 8];
        }
    } else {
        int e = (bid - NCAST - NW1 - NW2) * 256 + t;
        if (e < E) atomicAdd(&counts[ei[E + e]], 1);
    }
}

// ---------------- CSR scan: single-pass chunked exclusive scan of (counts[i]+1) ----------------
__global__ void k_scan(const int* __restrict__ counts, int* rowptr, int* cursor, int n) {
    __shared__ int s[1024];
    int t = threadIdx.x;
    const int CH = (NN + 1023) / 1024;     // 10
    int base = t * CH;
    int loc[CH];
    int sum = 0;
#pragma unroll
    for (int i = 0; i < CH; i++) {
        int idx = base + i;
        int v = (idx < n) ? (counts[idx] + 1) : 0;
        loc[i] = sum;
        sum += v;
    }
    s[t] = sum;
    __syncthreads();
    for (int off = 1; off < 1024; off <<= 1) {
        int add = (t >= off) ? s[t - off] : 0;
        __syncthreads();
        s[t] += add;
        __syncthreads();
    }
    int pre = (t > 0) ? s[t - 1] : 0;
#pragma unroll
    for (int i = 0; i < CH; i++) {
        int idx = base + i;
        if (idx < n) { int ex = pre + loc[i]; rowptr[idx] = ex; cursor[idx] = ex; }
    }
    if (t == 1023) rowptr[n] = s[1023];
}

// ---------------- async global->LDS helper ----------------
__device__ __forceinline__ void gl2lds16(const void* g, void* l) {
    __builtin_amdgcn_global_load_lds((const __attribute__((address_space(1))) void*)g,
                                     (__attribute__((address_space(3))) void*)l, 16, 0, 0);
}

// ---------------- fp16 MFMA GEMM + fused attention logits + optional CSR-fill side-job ----------------
template<int MFRAG>
__global__ __launch_bounds__(256, 2) void k_gemm(const _Float16* __restrict__ A,
                                                 const _Float16* __restrict__ Bt,
                                                 _Float16* __restrict__ C, int K, int N,
                                                 int NTN,
                                                 const float* __restrict__ asf,
                                                 const float* __restrict__ adf,
                                                 float* __restrict__ as,
                                                 float* __restrict__ ad,
                                                 int headw, int nblk,
                                                 const int* __restrict__ ei,
                                                 int* __restrict__ cursor,
                                                 int* __restrict__ colidx, int E) {
    constexpr int BM   = MFRAG * 32;
    constexpr int ABUF = BM * 32;               // fp16 elems per A buffer
    constexpr int ASL  = BM / 64;               // A staging slots per thread
    constexpr int WVM  = 0x0F70 | (ASL + 2);    // vmcnt <= loads-per-stage
    __shared__ char smem[3 * ABUF * 2 + 3 * 8192] __attribute__((aligned(16)));
    _Float16* As = (_Float16*)smem;
    _Float16* Bs = (_Float16*)(smem + 3 * ABUF * 2);

    int bid = blockIdx.x;
    if (bid >= nblk) {                          // CSR fill side-job
        int i = (bid - nblk) * 256 + threadIdx.x;
        if (i < E + NN) {
            int s, d;
            if (i < E) { s = ei[i]; d = ei[E + i]; }
            else       { s = i - E; d = i - E; }
            int pos = atomicAdd(&cursor[d], 1);
            colidx[pos] = s;
        }
        return;
    }
    int r = bid & 7, qb = bid >> 3;
    int n_t = qb % NTN;
    int m_t = r + 8 * (qb / NTN);
    int m0 = m_t * BM;
    int n0 = n_t * 128;
    int t = threadIdx.x;
    int lane = t & 63, wave = t >> 6;
    int wr = wave >> 1, wc = wave & 1;
    int lrow = lane & 15, q = lane >> 4;

    f32x4 acc[MFRAG][4] = {};

    int sA[ASL], sB[2];
#pragma unroll
    for (int i = 0; i < ASL; i++) sA[i] = t + 256 * i;
#pragma unroll
    for (int i = 0; i < 2; i++) sB[i] = t + 256 * i;
    const _Float16* Ar[ASL];
    const _Float16* Br[2];
#pragma unroll
    for (int i = 0; i < ASL; i++) {
        int row = sA[i] >> 2, gq = (sA[i] & 3) ^ ((sA[i] >> 3) & 3);
        Ar[i] = A + (long)(m0 + row) * K + gq * 8;
    }
#pragma unroll
    for (int i = 0; i < 2; i++) {
        int row = sB[i] >> 2, gq = (sB[i] & 3) ^ ((sB[i] >> 3) & 3);
        Br[i] = Bt + (long)(n0 + row) * K + gq * 8;
    }

    int aoff[MFRAG], boff[4];
#pragma unroll
    for (int i = 0; i < MFRAG; i++) {
        int rowa = wr * (MFRAG * 16) + i * 16 + lrow;
        aoff[i] = rowa * 32 + ((q ^ ((rowa >> 1) & 3)) << 3);
    }
#pragma unroll
    for (int i = 0; i < 4; i++) {
        int rowb = wc * 64 + i * 16 + lrow;
        boff[i] = rowb * 32 + ((q ^ ((rowb >> 1) & 3)) << 3);
    }

    auto stage = [&](int it, int buf) {
        int k0 = it << 5;
#pragma unroll
        for (int i = 0; i < ASL; i++) gl2lds16(Ar[i] + k0, &As[buf * ABUF + sA[i] * 8]);
#pragma unroll
        for (int i = 0; i < 2; i++) gl2lds16(Br[i] + k0, &Bs[buf * 4096 + sB[i] * 8]);
    };

    int nk = K >> 5;
    stage(0, 0);
    stage(1, 1);
    int cur = 0;
    for (int it = 0; it < nk; it++) {
        if (it + 1 < nk) __builtin_amdgcn_s_waitcnt(WVM);
        else             __builtin_amdgcn_s_waitcnt(0x0F70);
        __builtin_amdgcn_s_barrier();
        int nxt = cur + 2; if (nxt >= 3) nxt -= 3;
        if (it + 2 < nk) stage(it + 2, nxt);

        f16x8 af[MFRAG], bf[4];
#pragma unroll
        for (int i = 0; i < MFRAG; i++) af[i] = *(const f16x8*)&As[cur * ABUF + aoff[i]];
#pragma unroll
        for (int i = 0; i < 4; i++) bf[i] = *(const f16x8*)&Bs[cur * 4096 + boff[i]];
#pragma unroll
        for (int mt = 0; mt < MFRAG; mt++)
#pragma unroll
            for (int nt = 0; nt < 4; nt++)
                acc[mt][nt] = __builtin_amdgcn_mfma_f32_16x16x32_f16(bf[nt], af[mt], acc[mt][nt], 0, 0, 0);
        cur = (cur + 1 == 3) ? 0 : cur + 1;
    }

#pragma unroll
    for (int mt = 0; mt < MFRAG; mt++) {
        int m = m0 + wr * (MFRAG * 16) + mt * 16 + lrow;
#pragma unroll
        for (int nt = 0; nt < 4; nt++) {
            int n = n0 + wc * 64 + nt * 16 + q * 4;
            f16x4 o = {(_Float16)acc[mt][nt][0], (_Float16)acc[mt][nt][1],
                       (_Float16)acc[mt][nt][2], (_Float16)acc[mt][nt][3]};
            *(f16x4*)(C + (long)m * N + n) = o;
        }
    }

    // ---- fused logits: as/ad = h-row . asf/adf per head ----
    float4 av[4], dvv[4];
#pragma unroll
    for (int nt = 0; nt < 4; nt++) {
        av[nt]  = *(const float4*)(asf + n0 + wc * 64 + nt * 16 + q * 4);
        dvv[nt] = *(const float4*)(adf + n0 + wc * 64 + nt * 16 + q * 4);
    }
    __syncthreads();
    float* sAs = (float*)smem;
    float* sAd = (float*)smem + BM * 2;
#pragma unroll
    for (int mt = 0; mt < MFRAG; mt++) {
        float ps = 0.f, pd = 0.f;
#pragma unroll
        for (int nt = 0; nt < 4; nt++) {
            ps += acc[mt][nt][0] * av[nt].x + acc[mt][nt][1] * av[nt].y
                + acc[mt][nt][2] * av[nt].z + acc[mt][nt][3] * av[nt].w;
            pd += acc[mt][nt][0] * dvv[nt].x + acc[mt][nt][1] * dvv[nt].y
                + acc[mt][nt][2] * dvv[nt].z + acc[mt][nt][3] * dvv[nt].w;
        }
        ps += __shfl_xor(ps, 16); ps += __shfl_xor(ps, 32);
        pd += __shfl_xor(pd, 16); pd += __shfl_xor(pd, 32);
        if (q == 0) {
            int rl = wr * (MFRAG * 16) + mt * 16 + lrow;
            sAs[rl * 2 + wc] = ps;
            sAd[rl * 2 + wc] = pd;
        }
    }
    __syncthreads();
    if (t < BM) {
        int m = m0 + t;
        if (m < NN) {
            int hb = n0 / headw;
            if (headw == 128) {
                as[m * NH + hb] = sAs[t * 2] + sAs[t * 2 + 1];
                ad[m * NH + hb] = sAd[t * 2] + sAd[t * 2 + 1];
            } else {
                as[m * NH + hb]     = sAs[t * 2];
                as[m * NH + hb + 1] = sAs[t * 2 + 1];
                ad[m * NH + hb]     = sAd[t * 2];
                ad[m * NH + hb + 1] = sAd[t * 2 + 1];
            }
        }
    }
}

// ---------------- layer-1: FUSED softmax + wide-row aggregation -> A2 fp16 (R11-proven) ----------------
// 320 threads. Softmax: wave w computes alpha for heads 2w,2w+1 into LDS
// (deg<=64 fast path keeps logits in registers — read ONCE). Gather: thread t
// owns channels 4t..4t+3 (head = t>>5), f16x4, j-loop unrolled x4. grid = MP.
__global__ __launch_bounds__(320) void k_agg1(const int* __restrict__ rowptr,
                                              const int* __restrict__ colidx,
                                              const float* __restrict__ as,
                                              const float* __restrict__ ad,
                                              const _Float16* __restrict__ h,
                                              const float* __restrict__ bias,
                                              _Float16* __restrict__ A2) {
    __shared__ int sidx[64];
    __shared__ float sal[64 * NH];
    int n = blockIdx.x, t = threadIdx.x;
    if (n >= NN) {
        f16x4 z = {(_Float16)0.f, (_Float16)0.f, (_Float16)0.f, (_Float16)0.f};
        *(f16x4*)(A2 + (long)n * HC1 + 4 * t) = z;
        return;
    }
    int k0 = rowptr[n], deg = rowptr[n + 1] - k0;
    int w = t >> 6, lane = t & 63;
    int hd = t >> 5;
    float acc[4] = {0, 0, 0, 0};

    if (deg <= 64) {
        int src = (lane < deg) ? colidx[k0 + lane] : 0;
        float2 adv = *(const float2*)(ad + n * NH + 2 * w);
        float e0 = -1e30f, e1 = -1e30f;
        if (lane < deg) {
            float2 avv = *(const float2*)(as + (long)src * NH + 2 * w);
            e0 = leaky(avv.x + adv.x);
            e1 = leaky(avv.y + adv.y);
        }
        float m0 = e0, m1 = e1;
        for (int m = 32; m; m >>= 1) {
            m0 = fmaxf(m0, __shfl_xor(m0, m));
            m1 = fmaxf(m1, __shfl_xor(m1, m));
        }
        float x0 = (lane < deg) ? __expf(e0 - m0) : 0.f;
        float x1 = (lane < deg) ? __expf(e1 - m1) : 0.f;
        float s0 = x0, s1 = x1;
        for (int m = 32; m; m >>= 1) {
            s0 += __shfl_xor(s0, m);
            s1 += __shfl_xor(s1, m);
        }
        if (lane < deg) {
            sal[lane * NH + 2 * w]     = x0 / (s0 + 1e-16f);
            sal[lane * NH + 2 * w + 1] = x1 / (s1 + 1e-16f);
            if (w == 0) sidx[lane] = src;
        }
        __syncthreads();
        int j = 0;
        for (; j + 4 <= deg; j += 4) {            // 4 loads in flight
            int sj0 = sidx[j], sj1 = sidx[j + 1], sj2 = sidx[j + 2], sj3 = sidx[j + 3];
            float a0 = sal[j * NH + hd], a1 = sal[(j + 1) * NH + hd];
            float a2 = sal[(j + 2) * NH + hd], a3 = sal[(j + 3) * NH + hd];
            f16x4 v0 = *(const f16x4*)(h + (long)sj0 * HC1 + 4 * t);
            f16x4 v1 = *(const f16x4*)(h + (long)sj1 * HC1 + 4 * t);
            f16x4 v2 = *(const f16x4*)(h + (long)sj2 * HC1 + 4 * t);
            f16x4 v3 = *(const f16x4*)(h + (long)sj3 * HC1 + 4 * t);
#pragma unroll
            for (int i = 0; i < 4; i++)
                acc[i] += a0 * (float)v0[i] + a1 * (float)v1[i]
                        + a2 * (float)v2[i] + a3 * (float)v3[i];
        }
        for (; j < deg; j++) {
            int src2 = sidx[j];
            float a = sal[j * NH + hd];
            f16x4 v = *(const f16x4*)(h + (long)src2 * HC1 + 4 * t);
#pragma unroll
            for (int i = 0; i < 4; i++) acc[i] += a * (float)v[i];
        }
    } else {
        float2 adv = *(const float2*)(ad + n * NH + 2 * w);
        float m0 = -1e30f, m1 = -1e30f;
        for (int j = lane; j < deg; j += 64) {
            float2 avv = *(const float2*)(as + (long)colidx[k0 + j] * NH + 2 * w);
            m0 = fmaxf(m0, leaky(avv.x + adv.x));
            m1 = fmaxf(m1, leaky(avv.y + adv.y));
        }
        for (int m = 32; m; m >>= 1) {
            m0 = fmaxf(m0, __shfl_xor(m0, m));
            m1 = fmaxf(m1, __shfl_xor(m1, m));
        }
        float s0 = 0.f, s1 = 0.f;
        for (int j = lane; j < deg; j += 64) {
            float2 avv = *(const float2*)(as + (long)colidx[k0 + j] * NH + 2 * w);
            s0 += __expf(leaky(avv.x + adv.x) - m0);
            s1 += __expf(leaky(avv.y + adv.y) - m1);
        }
        for (int m = 32; m; m >>= 1) {
            s0 += __shfl_xor(s0, m);
            s1 += __shfl_xor(s1, m);
        }
        float i0 = 1.f / (s0 + 1e-16f), i1 = 1.f / (s1 + 1e-16f);
        for (int c0 = 0; c0 < deg; c0 += 64) {
            int cn = min(64, deg - c0);
            __syncthreads();
            if (lane < cn) {
                int src = colidx[k0 + c0 + lane];
                float2 avv = *(const float2*)(as + (long)src * NH + 2 * w);
                sal[lane * NH + 2 * w]     = __expf(leaky(avv.x + adv.x) - m0) * i0;
                sal[lane * NH + 2 * w + 1] = __expf(leaky(avv.y + adv.y) - m1) * i1;
                if (w == 0) sidx[lane] = src;
            }
            __syncthreads();
            for (int j = 0; j < cn; j++) {
                int src2 = sidx[j];
                float a = sal[j * NH + hd];
                f16x4 v = *(const f16x4*)(h + (long)src2 * HC1 + 4 * t);
#pragma unroll
                for (int i = 0; i < 4; i++) acc[i] += a * (float)v[i];
            }
        }
    }
    f16x4 o;
#pragma unroll
    for (int i = 0; i < 4; i++) {
        float x = acc[i] + bias[4 * t + i];
        o[i] = (_Float16)(x > 0.f ? x : 0.f);
    }
    *(f16x4*)(A2 + (long)n * HC1 + 4 * t) = o;
}

// ---------------- layer-2: FUSED softmax + aggregation + head mean + bias + relu (R11-proven) ----------------
__global__ __launch_bounds__(320) void k_agg2(const int* __restrict__ rowptr,
                                              const int* __restrict__ colidx,
                                              const float* __restrict__ as,
                                              const float* __restrict__ ad,
                                              const _Float16* __restrict__ h,
                                              const float* __restrict__ bias,
                                              float* __restrict__ out) {
    __shared__ int sidx[64];
    __shared__ float sal[64 * NH];
    __shared__ float facc[HC2];
    int n = blockIdx.x, t = threadIdx.x;
    int k0 = rowptr[n], deg = rowptr[n + 1] - k0;
    int w = t >> 6, lane = t & 63;
    int hd = t >> 5;
    float a0 = 0.f, a1 = 0.f;

    if (deg <= 64) {
        int src = (lane < deg) ? colidx[k0 + lane] : 0;
        float2 adv = *(const float2*)(ad + n * NH + 2 * w);
        float e0 = -1e30f, e1 = -1e30f;
        if (lane < deg) {
            float2 avv = *(const float2*)(as + (long)src * NH + 2 * w);
            e0 = leaky(avv.x + adv.x);
            e1 = leaky(avv.y + adv.y);
        }
        float m0 = e0, m1 = e1;
        for (int m = 32; m; m >>= 1) {
            m0 = fmaxf(m0, __shfl_xor(m0, m));
            m1 = fmaxf(m1, __shfl_xor(m1, m));
        }
        float x0 = (lane < deg) ? __expf(e0 - m0) : 0.f;
        float x1 = (lane < deg) ? __expf(e1 - m1) : 0.f;
        float s0 = x0, s1 = x1;
        for (int m = 32; m; m >>= 1) {
            s0 += __shfl_xor(s0, m);
            s1 += __shfl_xor(s1, m);
        }
        if (lane < deg) {
            sal[lane * NH + 2 * w]     = x0 / (s0 + 1e-16f);
            sal[lane * NH + 2 * w + 1] = x1 / (s1 + 1e-16f);
            if (w == 0) sidx[lane] = src;
        }
        __syncthreads();
        int j = 0;
        for (; j + 4 <= deg; j += 4) {            // 4 loads in flight
            int sj0 = sidx[j], sj1 = sidx[j + 1], sj2 = sidx[j + 2], sj3 = sidx[j + 3];
            float b0 = sal[j * NH + hd], b1 = sal[(j + 1) * NH + hd];
            float b2 = sal[(j + 2) * NH + hd], b3 = sal[(j + 3) * NH + hd];
            f16x2 v0 = *(const f16x2*)(h + (long)sj0 * HC2 + 2 * t);
            f16x2 v1 = *(const f16x2*)(h + (long)sj1 * HC2 + 2 * t);
            f16x2 v2 = *(const f16x2*)(h + (long)sj2 * HC2 + 2 * t);
            f16x2 v3 = *(const f16x2*)(h + (long)sj3 * HC2 + 2 * t);
            a0 += b0 * (float)v0[0] + b1 * (float)v1[0] + b2 * (float)v2[0] + b3 * (float)v3[0];
            a1 += b0 * (float)v0[1] + b1 * (float)v1[1] + b2 * (float)v2[1] + b3 * (float)v3[1];
        }
        for (; j < deg; j++) {
            int src2 = sidx[j];
            float a = sal[j * NH + hd];
            f16x2 v = *(const f16x2*)(h + (long)src2 * HC2 + 2 * t);
            a0 += a * (float)v[0];
            a1 += a * (float)v[1];
        }
    } else {
        float2 adv = *(const float2*)(ad + n * NH + 2 * w);
        float m0 = -1e30f, m1 = -1e30f;
        for (int j = lane; j < deg; j += 64) {
            float2 avv = *(const float2*)(as + (long)colidx[k0 + j] * NH + 2 * w);
            m0 = fmaxf(m0, leaky(avv.x + adv.x));
            m1 = fmaxf(m1, leaky(avv.y + adv.y));
        }
        for (int m = 32; m; m >>= 1) {
            m0 = fmaxf(m0, __shfl_xor(m0, m));
            m1 = fmaxf(m1, __shfl_xor(m1, m));
        }
        float s0 = 0.f, s1 = 0.f;
        for (int j = lane; j < deg; j += 64) {
            float2 avv = *(const float2*)(as + (long)colidx[k0 + j] * NH + 2 * w);
            s0 += __expf(leaky(avv.x + adv.x) - m0);
            s1 += __expf(leaky(avv.y + adv.y) - m1);
        }
        for (int m = 32; m; m >>= 1) {
            s0 += __shfl_xor(s0, m);
            s1 += __shfl_xor(s1, m);
        }
        float i0 = 1.f / (s0 + 1e-16f), i1 = 1.f / (s1 + 1e-16f);
        for (int c0 = 0; c0 < deg; c0 += 64) {
            int cn = min(64, deg - c0);
            __syncthreads();
            if (lane < cn) {
                int src = colidx[k0 + c0 + lane];
                float2 avv = *(const float2*)(as + (long)src * NH + 2 * w);
                sal[lane * NH + 2 * w]     = __expf(leaky(avv.x + adv.x) - m0) * i0;
                sal[lane * NH + 2 * w + 1] = __expf(leaky(avv.y + adv.y) - m1) * i1;
                if (w == 0) sidx[lane] = src;
            }
            __syncthreads();
            for (int j = 0; j < cn; j++) {
                int src2 = sidx[j];
                float a = sal[j * NH + hd];
                f16x2 v = *(const f16x2*)(h + (long)src2 * HC2 + 2 * t);
                a0 += a * (float)v[0];
                a1 += a * (float)v[1];
            }
        }
    }
    facc[2 * t] = a0;
    facc[2 * t + 1] = a1;
    __syncthreads();
    if (t < C2) {
        float s = 0.f;
#pragma unroll
        for (int hh = 0; hh < NH; hh++) s += facc[hh * C2 + t];
        s = s * 0.1f + bias[t];
        out[(long)n * C2 + t] = s > 0.f ? s : 0.f;
    }
}

// ---------------- host ----------------
extern "C" void kernel_launch(void* const* d_in, const int* in_sizes, int n_in,
                              void* d_out, int out_size, void* d_ws, size_t ws_size,
                              hipStream_t stream) {
    const float* x      = (const float*)d_in[0];
    const int*   ei     = (const int*)d_in[1];
    const float* W1     = (const float*)d_in[2];
    const float* asrc1  = (const float*)d_in[3];
    const float* adst1  = (const float*)d_in[4];
    const float* b1     = (const float*)d_in[5];
    const float* W2     = (const float*)d_in[6];
    const float* asrc2  = (const float*)d_in[7];
    const float* adst2  = (const float*)d_in[8];
    const float* b2     = (const float*)d_in[9];
    float* out = (float*)d_out;
    const int E  = in_sizes[1] / 2;
    const int EN = E + NN;

    char* base = (char*)d_ws;
    size_t o = 0;
    auto alloc = [&](size_t bytes) { size_t r = o; o += (bytes + 255) & ~(size_t)255; return r; };
    _Float16* A1    = (_Float16*)(base + alloc((size_t)MP * K1P * 2));
    _Float16* W1t   = (_Float16*)(base + alloc((size_t)HC1 * K1P * 2));
    _Float16* A2    = (_Float16*)(base + alloc((size_t)MP * HC1 * 2));
    _Float16* W2t   = (_Float16*)(base + alloc((size_t)HC2 * HC1 * 2));
    _Float16* h1pre = (_Float16*)(base + alloc((size_t)MP * HC1 * 2));
    _Float16* h2pre = (_Float16*)(base + alloc((size_t)MP * HC2 * 2));
    float* as1      = (float*)(base + alloc((size_t)NN * NH * 4));
    float* ad1      = (float*)(base + alloc((size_t)NN * NH * 4));
    float* as2      = (float*)(base + alloc((size_t)NN * NH * 4));
    float* ad2      = (float*)(base + alloc((size_t)NN * NH * 4));
    int* counts     = (int*)(base + alloc((size_t)(NN + 1) * 4));
    int* rowptr     = (int*)(base + alloc((size_t)(NN + 1) * 4));
    int* cursor     = (int*)(base + alloc((size_t)(NN + 1) * 4));
    int* colidx     = (int*)(base + alloc((size_t)EN * 4));
    (void)ws_size; (void)n_in; (void)out_size;

    const int NCNT = (E + 255) / 256;
    const int FILLB = (EN + 255) / 256;
    const int G1 = 8 * (MP / 256 / 8) * (HC1 / 128);   // 400 gemm1 blocks
    const int G2 = 8 * (MP / 128 / 8) * (HC2 / 128);   // 400 gemm2 blocks (MFRAG=4)

    // ---- zero counts, then fused prep (cast + transposes + edge count) ----
    hipMemsetAsync(counts, 0, (size_t)(NN + 1) * 4, stream);
    k_prep<<<NCAST + NW1 + NW2 + NCNT, 256, 0, stream>>>(x, A1, W1, W1t, W2, W2t, ei, counts, E);
    // ---- CSR scan (rowptr/cursor) ----
    k_scan<<<1, 1024, 0, stream>>>(counts, rowptr, cursor, NN);
    // ---- layer 1 GEMM (+ fused logits) with CSR-fill side-job blocks ----
    k_gemm<8><<<G1 + FILLB, 256, 0, stream>>>(A1, W1t, h1pre, K1P, HC1, HC1 / 128,
                                              asrc1, adst1, as1, ad1, C1,
                                              G1, ei, cursor, colidx, E);
    // ---- layer 1: fused softmax/aggregate -> A2 (pad rows zeroed inside) ----
    k_agg1<<<MP, 320, 0, stream>>>(rowptr, colidx, as1, ad1, h1pre, b1, A2);
    // ---- layer 2 GEMM (+ fused logits), BM=128 ----
    k_gemm<4><<<G2, 256, 0, stream>>>(A2, W2t, h2pre, HC1, HC2, HC2 / 128,
                                      asrc2, adst2, as2, ad2, C2,
                                      G2, ei, cursor, colidx, E);
    // ---- layer 2: fused softmax/aggregate + head mean ----
    k_agg2<<<NN, 320, 0, stream>>>(rowptr, colidx, as2, ad2, h2pre, b2, out);
}